// Round 4
// baseline (154.745 us; speedup 1.0000x reference)
//
#include <hip/hip_runtime.h>
#include <math.h>

// ---------------------------------------------------------------------------
// CGLayer: message pass -> nonlinear CG square + mix -> (collapsed) relative
// CG with sum_j(sph) + mix -> global-norm normalize.
//
// Key identity: the sum over neighbor axis j commutes with the relative CG
// product and channel mix because v_rep is j-independent and everything is
// linear in sph. So we precompute S[l][b,i,n] = sum_j sph_l[b,i,j,n] and never
// materialize any NxN-channel intermediate. Total work ~0.43 GFLOP.
//
// v3: nonlinear mix reads weights from LDS (staged transposed, once per block)
// as ds_read_b128, instead of per-FMA scalar global loads.
// v4: replace hipMemsetAsync with a zeroing kernel (unambiguously
// graph-capture-legal); no other changes.
// ---------------------------------------------------------------------------

#define NN    128       // nodes per batch
#define NB    8         // batches
#define NC    16        // channels
#define NODES (NB*NN)   // 1024
#define CGTOT 615
#define OUTSZ (NODES*NC*9)   // 147456
#define QPAD  260       // padded row width (words): bank skew 4, 16B-aligned
#define WPAD  260

// pair p = l1*3+l2
constexpr int P_NK[9]      = {1,3,5,3,9,8,5,8,9};                // sum(2l+1) over valid l
constexpr int P_CGOFF[9]   = {0,1,10,35,44,125,245,270,390};     // slab offsets, total 615
constexpr int P_KOFF[9][3] = {{0,-1,-1},{-1,0,-1},{-1,-1,0},
                              {-1,0,-1},{0,1,4},{-1,0,3},
                              {-1,-1,0},{-1,0,3},{0,1,4}};       // k-offset of l inside slab
constexpr int P_TB[9][3]   = {{0,-1,-1},{-1,0,-1},{-1,-1,0},
                              {-1,256,-1},{256,512,256},{-1,768,512},
                              {-1,-1,768},{-1,1024,1024},{512,1280,1280}}; // nl channel base
constexpr int P_SLOTL[9][3]= {{0,-1,-1},{1,-1,-1},{2,-1,-1},
                              {1,-1,-1},{0,1,2},{1,2,-1},
                              {2,-1,-1},{1,2,-1},{0,1,2}};       // slot -> l
constexpr int P_LSLOT[9][3]= {{0,-1,-1},{-1,0,-1},{-1,-1,0},
                              {-1,0,-1},{0,1,2},{-1,0,1},
                              {-1,-1,0},{-1,0,1},{0,1,2}};       // l -> slot
constexpr int XOFF[3] = {0,16,64};   // layout of per-node feature vector [l][c][m]
constexpr int SOFF[3] = {0,1,4};     // layout of S[9]
constexpr int KKB[3]  = {0,1,4};     // kk base per l in concatenated output

// ---------------------------------------------------------------------------
// Compile-time Clebsch-Gordan table (Racah formula, double precision,
// Newton-iteration constexpr sqrt). Max factorial argument = 7.
// ---------------------------------------------------------------------------
constexpr double cfact(int n) { double r = 1.0; for (int i = 2; i <= n; ++i) r *= (double)i; return r; }
constexpr double csqrt(double x) {
    double g = (x > 1.0) ? x : 1.0;
    for (int i = 0; i < 40; ++i) g = 0.5 * (g + x / g);
    return g;
}
constexpr double ccg(int j1, int m1, int j2, int m2, int j3, int m3) {
    if (m3 != m1 + m2) return 0.0;
    double pre = csqrt((2.0*j3 + 1.0) * cfact(j3+j1-j2) * cfact(j3-j1+j2)
                       * cfact(j1+j2-j3) / cfact(j1+j2+j3+1));
    pre *= csqrt(cfact(j3+m3) * cfact(j3-m3) * cfact(j1-m1)
                 * cfact(j1+m1) * cfact(j2-m2) * cfact(j2+m2));
    double s = 0.0;
    int vmin = 0;
    if (j2-j3-m1 > vmin) vmin = j2-j3-m1;
    if (j1-j3+m2 > vmin) vmin = j1-j3+m2;
    int vmax = j1+j2-j3;
    if (j1-m1 < vmax) vmax = j1-m1;
    if (j2+m2 < vmax) vmax = j2+m2;
    for (int v = vmin; v <= vmax; ++v) {
        double t = 1.0 / (cfact(v) * cfact(j1+j2-j3-v) * cfact(j1-m1-v)
                          * cfact(j2+m2-v) * cfact(j3-j2+m1+v) * cfact(j3-j1-m2+v));
        s += (v & 1) ? -t : t;
    }
    return pre * s;
}
struct CGTable { float v[CGTOT]; };
constexpr CGTable make_cg() {
    CGTable T{};
    for (int p = 0; p < 9; ++p) {
        const int l1 = p/3, l2 = p%3, n2 = 2*l2+1, n1 = 2*l1+1, nk = P_NK[p];
        for (int i1 = 0; i1 < n1; ++i1)
            for (int i2 = 0; i2 < n2; ++i2)
                for (int l = 0; l <= 2; ++l) {
                    const int ko = P_KOFF[p][l];
                    if (ko < 0) continue;
                    for (int k = 0; k < 2*l+1; ++k) {
                        const int m1 = i1-l1, m2 = i2-l2, m = k-l;
                        T.v[P_CGOFF[p] + (i1*n2+i2)*nk + ko + k] =
                            (float)((m1+m2 == m) ? ccg(l1, m1, l2, m2, l, m) : 0.0);
                    }
                }
    }
    return T;
}
__device__ constexpr CGTable CG_TAB = make_cg();   // folds to FMA literals after unroll

// ---------------------------------------------------------------------------
// Zero the 3 norm accumulators (graph-capture-safe, runs every launch).
// ---------------------------------------------------------------------------
__global__ void cg_zero(float* __restrict__ nrm) {
    if (threadIdx.x < 4) nrm[threadIdx.x] = 0.f;
}

// ---------------------------------------------------------------------------
// Main: one block per node (b,i). 256 threads, 4 waves. 1024 blocks, 2/CU.
// ---------------------------------------------------------------------------
__global__ __launch_bounds__(256) void cg_main(
    const float* __restrict__ v0,  const float* __restrict__ v1,  const float* __restrict__ v2,
    const float* __restrict__ sp0, const float* __restrict__ sp1, const float* __restrict__ sp2,
    const int*   __restrict__ conn,
    const float* __restrict__ wnl0, const float* __restrict__ wnl1, const float* __restrict__ wnl2,
    const float* __restrict__ wrl0, const float* __restrict__ wrl1, const float* __restrict__ wrl2,
    float* __restrict__ outv, float* __restrict__ nrm)
{
    const int node = blockIdx.x;            // b*128 + i
    const int b = node >> 7, i = node & 127;
    const int t = threadIdx.x;

    __shared__ float connF[NN];
    __shared__ float xls[144];        // v_mp    [l][c][m] at XOFF[l]+c*(2l+1)+m
    __shared__ float x2 [144];        // v_mix_nl, same layout
    __shared__ float Sls[12];         // S[l][n] at SOFF[l]+n
    __shared__ float Sp [72];         // S partials (9 entries x 8 j-chunks)
    __shared__ float psq[144];
    __shared__ float Tp [2][16*9];    // rel products [buf][c][kk]
    __shared__ __align__(16) float QT[2][9*QPAD];   // outer products [buf][z][cd]
    __shared__ __align__(16) float WT[3*16*WPAD];   // staged weights [slot*16+co][cd]

    // owner mapping (threads 0..143 own one output (l, k, co))
    const int  kk  = t >> 4;                 // 0..15 (only 0..8 own)
    const int  co  = t & 15;
    const int  myl = (kk == 0) ? 0 : ((kk < 4) ? 1 : 2);
    const int  myk = kk - KKB[myl];
    const bool owner = (t < 144);

    // ---- stage conn row ------------------------------------------------
    if (t < NN) connF[t] = (float)conn[(b*NN + i)*NN + t];
    __syncthreads();

    // ---- phase 1: v_mp (threads 0..143) and S partials (144..215) ------
    if (t < 144) {
        int l, c, m; const float* V;
        if (t < 16)      { l = 0; c = t;        m = 0;        V = v0; }
        else if (t < 64) { l = 1; int u = t-16; c = u/3; m = u%3; V = v1; }
        else             { l = 2; int u = t-64; c = u/5; m = u%5; V = v2; }
        const int nm = 2*l + 1;
        const int stride = NC*nm;
        const float* base = V + ((size_t)b*NN*NC + c)*nm + m;
        float a0 = 0.f, a1 = 0.f, a2 = 0.f, a3 = 0.f;
        for (int j = 0; j < NN; j += 4) {
            a0 = fmaf(connF[j+0], base[(size_t)(j+0)*stride], a0);
            a1 = fmaf(connF[j+1], base[(size_t)(j+1)*stride], a1);
            a2 = fmaf(connF[j+2], base[(size_t)(j+2)*stride], a2);
            a3 = fmaf(connF[j+3], base[(size_t)(j+3)*stride], a3);
        }
        xls[t] = (a0 + a1) + (a2 + a3);          // index == XOFF[l]+c*nm+m == t
    } else if (t < 216) {
        int e = (t - 144) >> 3, jc = (t - 144) & 7;
        int l = (e == 0) ? 0 : ((e < 4) ? 1 : 2);
        int n = e - SOFF[l];
        int nm = 2*l + 1;
        const float* SPH = (l == 0) ? sp0 : ((l == 1) ? sp1 : sp2);
        const float* basep = SPH + ((size_t)(b*NN + i))*NN*nm + n;
        float acc = 0.f;
        for (int j = jc*16; j < jc*16 + 16; ++j) acc += basep[(size_t)j*nm];
        Sp[t - 144] = acc;
    }
    __syncthreads();
    if (t < 9) {
        float a = 0.f;
        for (int q = 0; q < 8; ++q) a += Sp[t*8 + q];
        Sls[t] = a;
    }
    __syncthreads();

    // ---- phase 2: nonlinear CG square + mix with w_nl ------------------
    // Per pair: A-step (QT dbuf write) -> bar -> stage weights to WT -> bar
    // -> mix. WT single-buffered: pair p+1's stage happens after the first
    // barrier of pair p+1, by which time pair p's mix readers are done.
    // QT dbuf: A(p+1) overlaps mix(p) readers (other buffer); A(p+2) rewrites
    // buf p&1 only after bar2(p+1), which mix(p) readers passed at bar1(p+1).
    float vmix = 0.f;       // owner accumulator: v_mix_nl[myl][co][myk]
    #pragma unroll
    for (int p = 0; p < 9; ++p) {
        const int l1 = p / 3, l2 = p % 3;
        const int n1 = 2*l1 + 1, n2 = 2*l2 + 1, nkc = P_NK[p];
        // A: Q[cd][z] = sum_{m,n} x[l1][c][m] x[l2][d][n] CG[m,n,k]
        {
            const int c = t >> 4, d = t & 15;
            float q[9];
            #pragma unroll
            for (int z = 0; z < 9; ++z) q[z] = 0.f;
            const float* xa = &xls[XOFF[l1] + c*n1];
            const float* xb = &xls[XOFF[l2] + d*n2];
            #pragma unroll
            for (int i1 = 0; i1 < n1; ++i1) {
                const float a = xa[i1];
                #pragma unroll
                for (int i2 = 0; i2 < n2; ++i2) {
                    const float prod = a * xb[i2];
                    #pragma unroll
                    for (int l = 0; l < 3; ++l) {
                        const int ko = P_KOFF[p][l];
                        if (ko >= 0) {
                            const int k = i1 + i2 - l1 - l2 + l;   // the only nonzero k
                            if (k >= 0 && k < 2*l + 1)
                                q[ko + k] = fmaf(prod,
                                    CG_TAB.v[P_CGOFF[p] + (i1*n2 + i2)*nkc + ko + k],
                                    q[ko + k]);
                        }
                    }
                }
            }
            #pragma unroll
            for (int z = 0; z < 9; ++z)
                if (z < nkc) QT[p & 1][z*QPAD + t] = q[z];   // conflict-free writes
        }
        __syncthreads();
        // stage weights for this pair's valid l-chunks, transposed into LDS
        #pragma unroll
        for (int s = 0; s < 3; ++s) {
            const int ls = P_SLOTL[p][s];
            if (ls >= 0) {
                const float* Wt = (ls == 0) ? wnl0 : ((ls == 1) ? wnl1 : wnl2);
                const float4* src = (const float4*)(Wt + ((size_t)P_TB[p][ls] + t)*NC);
                const float4 r0 = src[0], r1 = src[1], r2 = src[2], r3 = src[3];
                float* wb = &WT[(size_t)s*16*WPAD + t];
                wb[ 0*WPAD] = r0.x; wb[ 1*WPAD] = r0.y; wb[ 2*WPAD] = r0.z; wb[ 3*WPAD] = r0.w;
                wb[ 4*WPAD] = r1.x; wb[ 5*WPAD] = r1.y; wb[ 6*WPAD] = r1.z; wb[ 7*WPAD] = r1.w;
                wb[ 8*WPAD] = r2.x; wb[ 9*WPAD] = r2.y; wb[10*WPAD] = r2.z; wb[11*WPAD] = r2.w;
                wb[12*WPAD] = r3.x; wb[13*WPAD] = r3.y; wb[14*WPAD] = r3.z; wb[15*WPAD] = r3.w;
            }
        }
        __syncthreads();
        // mix: owner (myl,myk,co) accumulates sum_{cd} Q[cd,kl] * WT[co,cd]
        if (owner) {
            const int ko = P_KOFF[p][myl];
            if (ko >= 0) {
                const int kl = ko + myk;
                const int sl = P_LSLOT[p][myl];
                const float4* qv = (const float4*)&QT[p & 1][kl*QPAD];
                const float4* wv = (const float4*)&WT[(size_t)(sl*16 + co)*WPAD];
                float a0 = 0.f, a1 = 0.f;
                #pragma unroll 8
                for (int u = 0; u < 64; ++u) {
                    const float4 q = qv[u];          // ds_read_b128, 16-way broadcast
                    const float4 w = wv[u];          // ds_read_b128
                    a0 = fmaf(q.x, w.x, a0);
                    a1 = fmaf(q.y, w.y, a1);
                    a0 = fmaf(q.z, w.z, a0);
                    a1 = fmaf(q.w, w.w, a1);
                }
                vmix += a0 + a1;
            }
        }
    }

    // stash v_mix_nl into LDS feature layout
    if (owner) x2[XOFF[myl] + co*(2*myl + 1) + myk] = vmix;
    __syncthreads();

    // ---- phase 3: collapsed relative CG (with S) + mix with w_rel ------
    float y = 0.f;          // owner accumulator: v_sum[myl][co][myk]
    #pragma unroll
    for (int p = 0; p < 9; ++p) {
        const int l1 = p / 3, l2 = p % 3;
        const int n1 = 2*l1 + 1, n2 = 2*l2 + 1, nkc = P_NK[p];
        if (t < 16) {
            const int c = t;
            float q[9];
            #pragma unroll
            for (int z = 0; z < 9; ++z) q[z] = 0.f;
            const float* xa = &x2[XOFF[l1] + c*n1];
            const float* sb = &Sls[SOFF[l2]];
            #pragma unroll
            for (int i1 = 0; i1 < n1; ++i1) {
                const float a = xa[i1];
                #pragma unroll
                for (int i2 = 0; i2 < n2; ++i2) {
                    const float prod = a * sb[i2];
                    #pragma unroll
                    for (int l = 0; l < 3; ++l) {
                        const int ko = P_KOFF[p][l];
                        if (ko >= 0) {
                            const int k = i1 + i2 - l1 - l2 + l;
                            if (k >= 0 && k < 2*l + 1)
                                q[ko + k] = fmaf(prod,
                                    CG_TAB.v[P_CGOFF[p] + (i1*n2 + i2)*nkc + ko + k],
                                    q[ko + k]);
                        }
                    }
                }
            }
            #pragma unroll
            for (int z = 0; z < 9; ++z)
                if (z < nkc) Tp[p & 1][t*nkc + z] = q[z];
        }
        __syncthreads();
        if (owner) {
            const int ko = P_KOFF[p][myl];
            if (ko >= 0) {
                const int kl = ko + myk;
                const float* wp = (myl == 0) ? wrl0 : ((myl == 1) ? wrl1 : wrl2);
                const int   tb = P_TB[p][myl] >> 4;    // rel chunks are 16 channels
                float a = 0.f;
                #pragma unroll
                for (int c = 0; c < 16; ++c)
                    a = fmaf(Tp[p & 1][c*nkc + kl], wp[(size_t)(tb + c)*NC + co], a);
                y += a;
            }
        }
    }

    // ---- write un-normalized output + block sum-of-squares -------------
    __syncthreads();
    if (owner) {
        outv[(size_t)node*144 + co*9 + kk] = y;
        psq[t] = y * y;
    }
    __syncthreads();
    if (t < 3) {
        const int lo = (t == 0) ? 0 : ((t == 1) ? 16 : 64);
        const int hi = (t == 0) ? 16 : ((t == 1) ? 64 : 144);
        float s = 0.f;
        for (int z = lo; z < hi; ++z) s += psq[z];
        atomicAdd(&nrm[t], s);
    }
}

// ---------------------------------------------------------------------------
// Normalize d_out in place: out = p / sqrt(nf_l / 16)
// ---------------------------------------------------------------------------
__global__ void cg_norm(float* __restrict__ outv, const float* __restrict__ nrm) {
    int idx = blockIdx.x * blockDim.x + threadIdx.x;
    if (idx >= OUTSZ) return;
    int kk = idx % 9;
    int l  = (kk == 0) ? 0 : ((kk < 4) ? 1 : 2);
    outv[idx] = outv[idx] / sqrtf(nrm[l] * (1.0f / 16.0f));
}

// ---------------------------------------------------------------------------
extern "C" void kernel_launch(void* const* d_in, const int* in_sizes, int n_in,
                              void* d_out, int out_size, void* d_ws, size_t ws_size,
                              hipStream_t stream) {
    (void)n_in; (void)out_size; (void)ws_size;
    const float *v0,*v1,*v2,*sp0,*sp1,*sp2,*wnl0,*wnl1,*wnl2,*wrl0,*wrl1,*wrl2;
    const int* conn;
    if (in_sizes[1] == 131072) {
        // setup_inputs() dict order: v0, sph0, v1, sph1, v2, sph2, conn,
        //                            wnl0, wrl0, wnl1, wrl1, wnl2, wrl2
        v0   = (const float*)d_in[0];  sp0 = (const float*)d_in[1];
        v1   = (const float*)d_in[2];  sp1 = (const float*)d_in[3];
        v2   = (const float*)d_in[4];  sp2 = (const float*)d_in[5];
        conn = (const int*)  d_in[6];
        wnl0 = (const float*)d_in[7];  wrl0 = (const float*)d_in[8];
        wnl1 = (const float*)d_in[9];  wrl1 = (const float*)d_in[10];
        wnl2 = (const float*)d_in[11]; wrl2 = (const float*)d_in[12];
    } else {
        // reference() signature order fallback
        v0   = (const float*)d_in[0];  v1  = (const float*)d_in[1];
        v2   = (const float*)d_in[2];
        conn = (const int*)  d_in[3];
        sp0  = (const float*)d_in[4];  sp1 = (const float*)d_in[5];
        sp2  = (const float*)d_in[6];
        wnl0 = (const float*)d_in[7];  wnl1 = (const float*)d_in[8];
        wnl2 = (const float*)d_in[9];
        wrl0 = (const float*)d_in[10]; wrl1 = (const float*)d_in[11];
        wrl2 = (const float*)d_in[12];
    }
    float* nrm = (float*)d_ws;     // 4 floats of scratch (3 used)
    float* out = (float*)d_out;

    hipLaunchKernelGGL(cg_zero, dim3(1),     dim3(64),  0, stream, nrm);
    hipLaunchKernelGGL(cg_main, dim3(NODES), dim3(256), 0, stream,
                       v0, v1, v2, sp0, sp1, sp2, conn,
                       wnl0, wnl1, wnl2, wrl0, wrl1, wrl2, out, nrm);
    hipLaunchKernelGGL(cg_norm, dim3((OUTSZ + 255) / 256), dim3(256), 0, stream,
                       out, nrm);
}